// Round 8
// baseline (286.210 us; speedup 1.0000x reference)
//
#include <hip/hip_runtime.h>
#include <stdint.h>

#define TT 512
#define NB 128
#define EM 256
#define UN 256

typedef float floatx4 __attribute__((ext_vector_type(4)));
typedef int v8i __attribute__((ext_vector_type(8)));

#define SCALE_Q 0x7B7B7B7BU   // e8m0 123 = 2^-4 (operands stored x16)
#define SCALE_A 0x7D7D7D7DU   // e8m0 125 = 2^-2  (h stored as 4*h)

// barrier without vmcnt drain: LDS-ordered only (no VMEM near barriers)
#define BAR() asm volatile("s_waitcnt lgkmcnt(0)\n\ts_barrier" ::: "memory")

__device__ inline unsigned char f2fp8(float f) {
    int pk = __builtin_amdgcn_cvt_pk_fp8_f32(f, f, 0, false);  // OCP e4m3 on gfx950
    return (unsigned char)(pk & 0xff);
}
// byte-select must be an immediate: shift word so target byte is byte 0
__device__ inline float fp8dec(uint32_t word, int sel) {
#if defined(__has_builtin)
#if __has_builtin(__builtin_amdgcn_cvt_f32_fp8)
    return __builtin_amdgcn_cvt_f32_fp8(word >> (8 * sel), 0);
#else
    unsigned char b = (word >> (8 * sel)) & 0xff;
    int s = b >> 7, e = (b >> 3) & 15, m = b & 7;
    float v = e ? ldexpf((float)(8 + m), e - 10) : ldexpf((float)m, -9);
    return s ? -v : v;
#endif
#else
    unsigned char b = (word >> (8 * sel)) & 0xff;
    int s = b >> 7, e = (b >> 3) & 15, m = b & 7;
    float v = e ? ldexpf((float)(8 + m), e - 10) : ldexpf((float)m, -9);
    return s ? -v : v;
#endif
}

// ---------------------------------------------------------------------------
// Kernel 1: blocks 0..31: W*16 -> fp8 B-frags (K=128 layout, for k_gemm).
//           blocks 32..63: U*16 -> fp8 B-frags (same layout, for k_rnn).
// frag[((kh*16+nt)*64+lane)*32 + j] = fp8(16*M[nt*16+(lane&15)][kh*128+(lane>>4)*32+j])
// ---------------------------------------------------------------------------
__global__ void k_pack(const float* __restrict__ W, const float* __restrict__ U,
                       unsigned char* __restrict__ wfrag8, unsigned char* __restrict__ ufrag8) {
    int bid = blockIdx.x;
    const float* src = (bid < 32) ? W : U;
    unsigned char* dstbase = (bid < 32) ? wfrag8 : ufrag8;
    int idx = (bid & 31) * 256 + threadIdx.x;  // 0..8191
    int jg   = idx & 3;
    int lane = (idx >> 2) & 63;
    int tile = idx >> 8;            // kh*16 + nt, 0..31
    int nt = tile & 15, kh = tile >> 4;
    int u  = nt * 16 + (lane & 15);
    int k0 = kh * 128 + (lane >> 4) * 32 + jg * 8;
    unsigned char* dst = dstbase + ((size_t)tile * 64 + lane) * 32 + jg * 8;
    #pragma unroll
    for (int j = 0; j < 8; j++) dst[j] = f2fp8(16.f * src[u * EM + k0 + j]);
}

// ---------------------------------------------------------------------------
// Kernel 2 (fp8): xw[b][t][u] = emb[sent]·W^T via mfma_scale 16x16x128.
// 1024 blocks x 256 thr. Wave w: rows (timesteps) w*16..w*16+15.
// Proven session-best version, unchanged.
// ---------------------------------------------------------------------------
__global__ __launch_bounds__(256, 2) void k_gemm(
    const int* __restrict__ sent, const float* __restrict__ emb,
    const unsigned char* __restrict__ wfrag8, unsigned char* __restrict__ xw8)
{
    __shared__ unsigned char gt[64][272];   // 64 rows x 256 cols fp8, +16 pad
    int w    = threadIdx.x >> 6;
    int lane = threadIdx.x & 63;
    int m  = lane & 15;
    int kg = lane >> 4;
    int row = blockIdx.x * 64 + w * 16 + m;
    int tok = sent[row];
    const float* arow = emb + (size_t)tok * EM;

    // A-frags: quantize this lane's 2 x 32-float slices to fp8 x16
    union { uint32_t d[8]; v8i v; } A[2];
    #pragma unroll
    for (int kh = 0; kh < 2; kh++) {
        const float* p = arow + kh * 128 + kg * 32;
        #pragma unroll
        for (int d = 0; d < 8; d++) {
            float4 f = *(const float4*)(p + 4 * d);
            int pk = __builtin_amdgcn_cvt_pk_fp8_f32(16.f * f.x, 16.f * f.y, 0, false);
            pk     = __builtin_amdgcn_cvt_pk_fp8_f32(16.f * f.z, 16.f * f.w, pk, true);
            A[kh].d[d] = (uint32_t)pk;
        }
    }

    const floatx4 zero4 = {0.f, 0.f, 0.f, 0.f};
    floatx4 acc[16];
    #pragma unroll
    for (int nt = 0; nt < 16; nt++) {
        union { uint4 u4[2]; v8i v; } B0, B1;
        const uint4* p0 = (const uint4*)(wfrag8 + ((size_t)(0 * 16 + nt) * 64 + lane) * 32);
        const uint4* p1 = (const uint4*)(wfrag8 + ((size_t)(1 * 16 + nt) * 64 + lane) * 32);
        B0.u4[0] = p0[0]; B0.u4[1] = p0[1];
        B1.u4[0] = p1[0]; B1.u4[1] = p1[1];
        floatx4 a = __builtin_amdgcn_mfma_scale_f32_16x16x128_f8f6f4(
                        A[0].v, B0.v, zero4, 0, 0, 0, SCALE_Q, 0, SCALE_Q);
        a = __builtin_amdgcn_mfma_scale_f32_16x16x128_f8f6f4(
                        A[1].v, B1.v, a, 0, 0, 0, SCALE_Q, 0, SCALE_Q);
        acc[nt] = a;
    }

    // D: row = w*16 + kg*4 + r (timestep), col = nt*16 + m (unit) -> fp8 x16
    int rloc = w * 16 + kg * 4;
    #pragma unroll
    for (int nt = 0; nt < 16; nt++) {
        #pragma unroll
        for (int r = 0; r < 4; r++) {
            gt[rloc + r][nt * 16 + m] = f2fp8(16.f * acc[nt][r]);
        }
    }
    __syncthreads();

    int rowbase = blockIdx.x * 64;
    #pragma unroll
    for (int r2 = 0; r2 < 16; r2++) {
        int rr = w * 16 + r2;
        uint32_t v = *(const uint32_t*)&gt[rr][lane * 4];
        *(uint32_t*)(xw8 + (size_t)(rowbase + rr) * UN + lane * 4) = v;
    }
}

// ---------------------------------------------------------------------------
// Kernel 3 (v15): R7's proven 159.4us kernel with exactly two chain-shortening
// edits, everything else byte-identical:
//   (1) split chained MFMA pair -> 2 independent accumulators + scalar add
//       (removes one MFMA result latency from the 512-long serial chain)
//   (2) xf folded into C-input of the first MFMA ({xf,0,0,0}; only acc[0]
//       is read) -- deletes the dependent +xf add; xf decode hides under
//       the A-frag ds_read
// ---------------------------------------------------------------------------
__global__ __launch_bounds__(256, 1) void k_rnn(
    const unsigned char* __restrict__ ufrag8, const unsigned char* __restrict__ xw8,
    const float* __restrict__ W1, const float* __restrict__ b1,
    const float* __restrict__ W2, const float* __restrict__ b2,
    float* __restrict__ out)
{
    __shared__ __align__(16) unsigned char hb8[2][256];
    __shared__ __align__(16) unsigned char xstage[64 * 256];   // 16 KB chunk
    __shared__ float partial[256];
    __shared__ float hid[32];
    const int t    = threadIdx.x;
    const int lane = t & 63;
    const int w    = t >> 6;
    const int kg   = lane >> 4;
    const int b    = blockIdx.x;

    // U fp8 B-frags -> registers: ufr8[q][kh], tile nt = 4w+q
    v8i ufr8[4][2];
    #pragma unroll
    for (int q = 0; q < 4; q++) {
        #pragma unroll
        for (int kh = 0; kh < 2; kh++) {
            const uint4* p = (const uint4*)(ufrag8 + ((size_t)(kh * 16 + 4 * w + q) * 64 + lane) * 32);
            union { uint4 u4[2]; v8i v; } cvt;
            cvt.u4[0] = p[0]; cvt.u4[1] = p[1];
            ufr8[q][kh] = cvt.v;
        }
    }

    const unsigned char* xwb = xw8 + (size_t)b * TT * UN;
    const int roff = t * 16;   // byte offset of this thread's 16B refresh slice

    // stage chunk 0 (steps 0..63): 256 thr x 4 x 16B = 16 KB
    uint4 xr[4];
    #pragma unroll
    for (int p = 0; p < 4; p++) xr[p] = *(const uint4*)(xwb + roff + p * 4096);
    #pragma unroll
    for (int p = 0; p < 4; p++) *(uint4*)&xstage[roff + p * 4096] = xr[p];

    hb8[0][t] = 0; hb8[1][t] = 0;
    __syncthreads();

    int cur = 0;
    const floatx4 zero4 = {0.f, 0.f, 0.f, 0.f};
    const int sel = lane >> 4;

    for (int s = 0; s < TT; s++) {
        const int ls = s & 63;
        uint32_t xword = *(const uint32_t*)&xstage[ls * 256 + (t & ~3)];
        float xf = fp8dec(xword, t & 3) * 0.0625f;   // /16
        floatx4 cx = {xf, 0.f, 0.f, 0.f};            // xf rides in C[0]

        // A-frags (fp8, 4*h): broadcast 32B reads per k-half
        const unsigned char* hc = hb8[cur];
        union { uint4 u4[2]; v8i v; } A0, A1;
        A0.u4[0] = *(const uint4*)(hc + kg * 32);
        A0.u4[1] = *(const uint4*)(hc + kg * 32 + 16);
        A1.u4[0] = *(const uint4*)(hc + 128 + kg * 32);
        A1.u4[1] = *(const uint4*)(hc + 128 + kg * 32 + 16);

        // 4 tiles x 2 k-halves: 8 INDEPENDENT MFMAs; xf pre-added via C[0]
        float z[4];
        #pragma unroll
        for (int q = 0; q < 4; q++) {
            floatx4 a0 = __builtin_amdgcn_mfma_scale_f32_16x16x128_f8f6f4(
                             A0.v, ufr8[q][0], cx, 0, 0, 0, SCALE_A, 0, SCALE_Q);
            floatx4 a1 = __builtin_amdgcn_mfma_scale_f32_16x16x128_f8f6f4(
                             A1.v, ufr8[q][1], zero4, 0, 0, 0, SCALE_A, 0, SCALE_Q);
            z[q] = a0[0] + a1[0];
        }

        float zz = (sel == 0) ? z[0] : (sel == 1) ? z[1] : (sel == 2) ? z[2] : z[3];

        // branchless tanh: accurate to ~1e-7, no exec-mask churn
        float e = __expf(2.f * zz);
        float hn = 1.f - 2.f * __builtin_amdgcn_rcpf(e + 1.f);

        hb8[cur ^ 1][t] = f2fp8(4.f * hn);

        if (ls == 60 && s + 68 <= TT) {
            const unsigned char* cb = xwb + (size_t)(s + 4) * UN;
            #pragma unroll
            for (int p = 0; p < 4; p++) xr[p] = *(const uint4*)(cb + roff + p * 4096);
        }
        if (ls == 63 && s + 65 <= TT) {
            BAR();
            #pragma unroll
            for (int p = 0; p < 4; p++) *(uint4*)&xstage[roff + p * 4096] = xr[p];
        }
        BAR();
        cur ^= 1;
    }

    // ---- head: hidden = relu(h @ W1 + b1), parallel over 256 threads
    // thread t: column t&31, K-segment t>>5 (32 of 256 k each); h = fp8/4
    {
        int col = t & 31, seg = t >> 5;
        float a = 0.f;
        #pragma unroll
        for (int kk = 0; kk < 32; kk++) {
            int k = seg * 32 + kk;
            uint32_t wd = *(const uint32_t*)&hb8[cur][k & ~3];
            a += fp8dec(wd, k & 3) * W1[k * 32 + col];
        }
        partial[t] = a;
    }
    __syncthreads();
    if (t < 32) {
        float acc = 0.f;
        #pragma unroll
        for (int i = 0; i < 8; i++) acc += partial[i * 32 + t];
        hid[t] = fmaxf(fmaf(0.25f, acc, b1[t]), 0.f);
    }
    __syncthreads();
    if (t == 0) {
        float l0 = b2[0], l1 = b2[1];
        #pragma unroll
        for (int i = 0; i < 32; i++) {
            float hv = hid[i];
            l0 += hv * W2[2 * i];
            l1 += hv * W2[2 * i + 1];
        }
        float mx2 = fmaxf(l0, l1);
        float e0 = __expf(l0 - mx2), e1 = __expf(l1 - mx2);
        float inv = 1.f / (e0 + e1);
        out[2 * b]     = e0 * inv;
        out[2 * b + 1] = e1 * inv;
    }
}

extern "C" void kernel_launch(void* const* d_in, const int* in_sizes, int n_in,
                              void* d_out, int out_size, void* d_ws, size_t ws_size,
                              hipStream_t stream) {
    const int*   sent = (const int*)d_in[0];
    const float* emb  = (const float*)d_in[1];
    const float* W    = (const float*)d_in[2];
    const float* U    = (const float*)d_in[3];
    const float* W1   = (const float*)d_in[4];
    const float* b1   = (const float*)d_in[5];
    const float* W2   = (const float*)d_in[6];
    const float* b2   = (const float*)d_in[7];
    float* out = (float*)d_out;

    unsigned char* xw8    = (unsigned char*)d_ws;                                   // 16 MB fp8 [B][T][U]
    unsigned char* wfrag8 = (unsigned char*)d_ws + (size_t)NB * TT * UN;            // 64 KB
    unsigned char* ufrag8 = wfrag8 + (size_t)UN * EM;                               // 64 KB

    k_pack<<<64, 256, 0, stream>>>(W, U, wfrag8, ufrag8);
    k_gemm<<<(NB * TT) / 64, 256, 0, stream>>>(sent, emb, wfrag8, xw8);
    k_rnn<<<NB, 256, 0, stream>>>(ufrag8, xw8, W1, b1, W2, b2, out);
}

// Round 9
// 275.120 us; speedup vs baseline: 1.0403x; 1.0403x over previous
//
#include <hip/hip_runtime.h>
#include <stdint.h>

#define TT 512
#define NB 128
#define EM 256
#define UN 256

typedef float floatx4 __attribute__((ext_vector_type(4)));
typedef int v8i __attribute__((ext_vector_type(8)));

#define SCALE_Q 0x7B7B7B7BU   // e8m0 123 = 2^-4 (operands stored x16)
#define SCALE_A 0x7D7D7D7DU   // e8m0 125 = 2^-2  (h stored as 4*h)

// barrier without vmcnt drain: LDS-ordered only (no VMEM near barriers)
#define BAR() asm volatile("s_waitcnt lgkmcnt(0)\n\ts_barrier" ::: "memory")

__device__ inline unsigned char f2fp8(float f) {
    int pk = __builtin_amdgcn_cvt_pk_fp8_f32(f, f, 0, false);  // OCP e4m3 on gfx950
    return (unsigned char)(pk & 0xff);
}
// byte-select must be an immediate: shift word so target byte is byte 0
__device__ inline float fp8dec(uint32_t word, int sel) {
#if defined(__has_builtin)
#if __has_builtin(__builtin_amdgcn_cvt_f32_fp8)
    return __builtin_amdgcn_cvt_f32_fp8(word >> (8 * sel), 0);
#else
    unsigned char b = (word >> (8 * sel)) & 0xff;
    int s = b >> 7, e = (b >> 3) & 15, m = b & 7;
    float v = e ? ldexpf((float)(8 + m), e - 10) : ldexpf((float)m, -9);
    return s ? -v : v;
#endif
#else
    unsigned char b = (word >> (8 * sel)) & 0xff;
    int s = b >> 7, e = (b >> 3) & 15, m = b & 7;
    float v = e ? ldexpf((float)(8 + m), e - 10) : ldexpf((float)m, -9);
    return s ? -v : v;
#endif
}

// ---------------------------------------------------------------------------
// Kernel 1: blocks 0..31: W*16 -> fp8 B-frags (K=128 layout, for k_gemm).
//           blocks 32..63: U*16 -> fp8 B-frags (same layout, for k_rnn).
// frag[((kh*16+nt)*64+lane)*32 + j] = fp8(16*M[nt*16+(lane&15)][kh*128+(lane>>4)*32+j])
// ---------------------------------------------------------------------------
__global__ void k_pack(const float* __restrict__ W, const float* __restrict__ U,
                       unsigned char* __restrict__ wfrag8, unsigned char* __restrict__ ufrag8) {
    int bid = blockIdx.x;
    const float* src = (bid < 32) ? W : U;
    unsigned char* dstbase = (bid < 32) ? wfrag8 : ufrag8;
    int idx = (bid & 31) * 256 + threadIdx.x;  // 0..8191
    int jg   = idx & 3;
    int lane = (idx >> 2) & 63;
    int tile = idx >> 8;            // kh*16 + nt, 0..31
    int nt = tile & 15, kh = tile >> 4;
    int u  = nt * 16 + (lane & 15);
    int k0 = kh * 128 + (lane >> 4) * 32 + jg * 8;
    unsigned char* dst = dstbase + ((size_t)tile * 64 + lane) * 32 + jg * 8;
    #pragma unroll
    for (int j = 0; j < 8; j++) dst[j] = f2fp8(16.f * src[u * EM + k0 + j]);
}

// ---------------------------------------------------------------------------
// Kernel 2 (fp8): xw[b][t][u] = emb[sent]·W^T via mfma_scale 16x16x128.
// 1024 blocks x 256 thr. Wave w: rows (timesteps) w*16..w*16+15.
// Proven session-best version, unchanged.
// ---------------------------------------------------------------------------
__global__ __launch_bounds__(256, 2) void k_gemm(
    const int* __restrict__ sent, const float* __restrict__ emb,
    const unsigned char* __restrict__ wfrag8, unsigned char* __restrict__ xw8)
{
    __shared__ unsigned char gt[64][272];   // 64 rows x 256 cols fp8, +16 pad
    int w    = threadIdx.x >> 6;
    int lane = threadIdx.x & 63;
    int m  = lane & 15;
    int kg = lane >> 4;
    int row = blockIdx.x * 64 + w * 16 + m;
    int tok = sent[row];
    const float* arow = emb + (size_t)tok * EM;

    // A-frags: quantize this lane's 2 x 32-float slices to fp8 x16
    union { uint32_t d[8]; v8i v; } A[2];
    #pragma unroll
    for (int kh = 0; kh < 2; kh++) {
        const float* p = arow + kh * 128 + kg * 32;
        #pragma unroll
        for (int d = 0; d < 8; d++) {
            float4 f = *(const float4*)(p + 4 * d);
            int pk = __builtin_amdgcn_cvt_pk_fp8_f32(16.f * f.x, 16.f * f.y, 0, false);
            pk     = __builtin_amdgcn_cvt_pk_fp8_f32(16.f * f.z, 16.f * f.w, pk, true);
            A[kh].d[d] = (uint32_t)pk;
        }
    }

    const floatx4 zero4 = {0.f, 0.f, 0.f, 0.f};
    floatx4 acc[16];
    #pragma unroll
    for (int nt = 0; nt < 16; nt++) {
        union { uint4 u4[2]; v8i v; } B0, B1;
        const uint4* p0 = (const uint4*)(wfrag8 + ((size_t)(0 * 16 + nt) * 64 + lane) * 32);
        const uint4* p1 = (const uint4*)(wfrag8 + ((size_t)(1 * 16 + nt) * 64 + lane) * 32);
        B0.u4[0] = p0[0]; B0.u4[1] = p0[1];
        B1.u4[0] = p1[0]; B1.u4[1] = p1[1];
        floatx4 a = __builtin_amdgcn_mfma_scale_f32_16x16x128_f8f6f4(
                        A[0].v, B0.v, zero4, 0, 0, 0, SCALE_Q, 0, SCALE_Q);
        a = __builtin_amdgcn_mfma_scale_f32_16x16x128_f8f6f4(
                        A[1].v, B1.v, a, 0, 0, 0, SCALE_Q, 0, SCALE_Q);
        acc[nt] = a;
    }

    // D: row = w*16 + kg*4 + r (timestep), col = nt*16 + m (unit) -> fp8 x16
    int rloc = w * 16 + kg * 4;
    #pragma unroll
    for (int nt = 0; nt < 16; nt++) {
        #pragma unroll
        for (int r = 0; r < 4; r++) {
            gt[rloc + r][nt * 16 + m] = f2fp8(16.f * acc[nt][r]);
        }
    }
    __syncthreads();

    int rowbase = blockIdx.x * 64;
    #pragma unroll
    for (int r2 = 0; r2 < 16; r2++) {
        int rr = w * 16 + r2;
        uint32_t v = *(const uint32_t*)&gt[rr][lane * 4];
        *(uint32_t*)(xw8 + (size_t)(rowbase + rr) * UN + lane * 4) = v;
    }
}

// ---------------------------------------------------------------------------
// Kernel 3 (v16): R7's proven 159.4us kernel (branchless tanh + parallel
// head) with ONE surgical edit, everything else byte-identical:
//   xf folded into C[0] of the first MFMA of each CHAINED pair (R8 showed
//   chained beats split by ~16us). Lane l reads element (row=4*kg, col=m)
//   which is lane-unique, so adding xf there is exact; deletes the
//   dependent zz+=xf add from the serial tail.
// ---------------------------------------------------------------------------
__global__ __launch_bounds__(256, 1) void k_rnn(
    const unsigned char* __restrict__ ufrag8, const unsigned char* __restrict__ xw8,
    const float* __restrict__ W1, const float* __restrict__ b1,
    const float* __restrict__ W2, const float* __restrict__ b2,
    float* __restrict__ out)
{
    __shared__ __align__(16) unsigned char hb8[2][256];
    __shared__ __align__(16) unsigned char xstage[64 * 256];   // 16 KB chunk
    __shared__ float partial[256];
    __shared__ float hid[32];
    const int t    = threadIdx.x;
    const int lane = t & 63;
    const int w    = t >> 6;
    const int kg   = lane >> 4;
    const int b    = blockIdx.x;

    // U fp8 B-frags -> registers: ufr8[q][kh], tile nt = 4w+q
    v8i ufr8[4][2];
    #pragma unroll
    for (int q = 0; q < 4; q++) {
        #pragma unroll
        for (int kh = 0; kh < 2; kh++) {
            const uint4* p = (const uint4*)(ufrag8 + ((size_t)(kh * 16 + 4 * w + q) * 64 + lane) * 32);
            union { uint4 u4[2]; v8i v; } cvt;
            cvt.u4[0] = p[0]; cvt.u4[1] = p[1];
            ufr8[q][kh] = cvt.v;
        }
    }

    const unsigned char* xwb = xw8 + (size_t)b * TT * UN;
    const int roff = t * 16;   // byte offset of this thread's 16B refresh slice

    // stage chunk 0 (steps 0..63): 256 thr x 4 x 16B = 16 KB
    uint4 xr[4];
    #pragma unroll
    for (int p = 0; p < 4; p++) xr[p] = *(const uint4*)(xwb + roff + p * 4096);
    #pragma unroll
    for (int p = 0; p < 4; p++) *(uint4*)&xstage[roff + p * 4096] = xr[p];

    hb8[0][t] = 0; hb8[1][t] = 0;
    __syncthreads();

    int cur = 0;
    const int sel = lane >> 4;

    for (int s = 0; s < TT; s++) {
        const int ls = s & 63;
        uint32_t xword = *(const uint32_t*)&xstage[ls * 256 + (t & ~3)];
        float xf = fp8dec(xword, t & 3) * 0.0625f;   // /16
        floatx4 cx = {xf, 0.f, 0.f, 0.f};            // xf rides in C[0]

        // A-frags (fp8, 4*h): broadcast 32B reads per k-half
        const unsigned char* hc = hb8[cur];
        union { uint4 u4[2]; v8i v; } A0, A1;
        A0.u4[0] = *(const uint4*)(hc + kg * 32);
        A0.u4[1] = *(const uint4*)(hc + kg * 32 + 16);
        A1.u4[0] = *(const uint4*)(hc + 128 + kg * 32);
        A1.u4[1] = *(const uint4*)(hc + 128 + kg * 32 + 16);

        // 4 tiles, chained K=128 x2 accumulate (R8: chained beats split);
        // xf pre-added via C[0] of the first MFMA in each chain
        float z[4];
        #pragma unroll
        for (int q = 0; q < 4; q++) {
            floatx4 acc = __builtin_amdgcn_mfma_scale_f32_16x16x128_f8f6f4(
                              A0.v, ufr8[q][0], cx, 0, 0, 0, SCALE_A, 0, SCALE_Q);
            acc = __builtin_amdgcn_mfma_scale_f32_16x16x128_f8f6f4(
                              A1.v, ufr8[q][1], acc, 0, 0, 0, SCALE_A, 0, SCALE_Q);
            z[q] = acc[0];
        }

        float zz = (sel == 0) ? z[0] : (sel == 1) ? z[1] : (sel == 2) ? z[2] : z[3];

        // branchless tanh: accurate to ~1e-7, no exec-mask churn
        float e = __expf(2.f * zz);
        float hn = 1.f - 2.f * __builtin_amdgcn_rcpf(e + 1.f);

        hb8[cur ^ 1][t] = f2fp8(4.f * hn);

        if (ls == 60 && s + 68 <= TT) {
            const unsigned char* cb = xwb + (size_t)(s + 4) * UN;
            #pragma unroll
            for (int p = 0; p < 4; p++) xr[p] = *(const uint4*)(cb + roff + p * 4096);
        }
        if (ls == 63 && s + 65 <= TT) {
            BAR();
            #pragma unroll
            for (int p = 0; p < 4; p++) *(uint4*)&xstage[roff + p * 4096] = xr[p];
        }
        BAR();
        cur ^= 1;
    }

    // ---- head: hidden = relu(h @ W1 + b1), parallel over 256 threads
    // thread t: column t&31, K-segment t>>5 (32 of 256 k each); h = fp8/4
    {
        int col = t & 31, seg = t >> 5;
        float a = 0.f;
        #pragma unroll
        for (int kk = 0; kk < 32; kk++) {
            int k = seg * 32 + kk;
            uint32_t wd = *(const uint32_t*)&hb8[cur][k & ~3];
            a += fp8dec(wd, k & 3) * W1[k * 32 + col];
        }
        partial[t] = a;
    }
    __syncthreads();
    if (t < 32) {
        float acc = 0.f;
        #pragma unroll
        for (int i = 0; i < 8; i++) acc += partial[i * 32 + t];
        hid[t] = fmaxf(fmaf(0.25f, acc, b1[t]), 0.f);
    }
    __syncthreads();
    if (t == 0) {
        float l0 = b2[0], l1 = b2[1];
        #pragma unroll
        for (int i = 0; i < 32; i++) {
            float hv = hid[i];
            l0 += hv * W2[2 * i];
            l1 += hv * W2[2 * i + 1];
        }
        float mx2 = fmaxf(l0, l1);
        float e0 = __expf(l0 - mx2), e1 = __expf(l1 - mx2);
        float inv = 1.f / (e0 + e1);
        out[2 * b]     = e0 * inv;
        out[2 * b + 1] = e1 * inv;
    }
}

extern "C" void kernel_launch(void* const* d_in, const int* in_sizes, int n_in,
                              void* d_out, int out_size, void* d_ws, size_t ws_size,
                              hipStream_t stream) {
    const int*   sent = (const int*)d_in[0];
    const float* emb  = (const float*)d_in[1];
    const float* W    = (const float*)d_in[2];
    const float* U    = (const float*)d_in[3];
    const float* W1   = (const float*)d_in[4];
    const float* b1   = (const float*)d_in[5];
    const float* W2   = (const float*)d_in[6];
    const float* b2   = (const float*)d_in[7];
    float* out = (float*)d_out;

    unsigned char* xw8    = (unsigned char*)d_ws;                                   // 16 MB fp8 [B][T][U]
    unsigned char* wfrag8 = (unsigned char*)d_ws + (size_t)NB * TT * UN;            // 64 KB
    unsigned char* ufrag8 = wfrag8 + (size_t)UN * EM;                               // 64 KB

    k_pack<<<64, 256, 0, stream>>>(W, U, wfrag8, ufrag8);
    k_gemm<<<(NB * TT) / 64, 256, 0, stream>>>(sent, emb, wfrag8, xw8);
    k_rnn<<<NB, 256, 0, stream>>>(ufrag8, xw8, W1, b1, W2, b2, out);
}

// Round 10
// 272.209 us; speedup vs baseline: 1.0514x; 1.0107x over previous
//
#include <hip/hip_runtime.h>
#include <stdint.h>

#define TT 512
#define NB 128
#define EM 256
#define UN 256

typedef float floatx4 __attribute__((ext_vector_type(4)));
typedef int v8i __attribute__((ext_vector_type(8)));

#define SCALE_Q 0x7B7B7B7BU   // e8m0 123 = 2^-4 (operands stored x16)
#define SCALE_A 0x7D7D7D7DU   // e8m0 125 = 2^-2  (h stored as 4*h)

// barrier without vmcnt drain: LDS-ordered only (no VMEM near barriers)
#define BAR() asm volatile("s_waitcnt lgkmcnt(0)\n\ts_barrier" ::: "memory")

__device__ inline unsigned char f2fp8(float f) {
    int pk = __builtin_amdgcn_cvt_pk_fp8_f32(f, f, 0, false);  // OCP e4m3 on gfx950
    return (unsigned char)(pk & 0xff);
}
// byte-select must be an immediate: shift word so target byte is byte 0
__device__ inline float fp8dec(uint32_t word, int sel) {
#if defined(__has_builtin)
#if __has_builtin(__builtin_amdgcn_cvt_f32_fp8)
    return __builtin_amdgcn_cvt_f32_fp8(word >> (8 * sel), 0);
#else
    unsigned char b = (word >> (8 * sel)) & 0xff;
    int s = b >> 7, e = (b >> 3) & 15, m = b & 7;
    float v = e ? ldexpf((float)(8 + m), e - 10) : ldexpf((float)m, -9);
    return s ? -v : v;
#endif
#else
    unsigned char b = (word >> (8 * sel)) & 0xff;
    int s = b >> 7, e = (b >> 3) & 15, m = b & 7;
    float v = e ? ldexpf((float)(8 + m), e - 10) : ldexpf((float)m, -9);
    return s ? -v : v;
#endif
}

// ---------------------------------------------------------------------------
// Kernel 1: blocks 0..31: W*16 -> fp8 B-frags (K=128 layout, for k_gemm).
//           blocks 32..63: U*16 -> fp8 B-frags (same layout, for k_rnn).
// frag[((kh*16+nt)*64+lane)*32 + j] = fp8(16*M[nt*16+(lane&15)][kh*128+(lane>>4)*32+j])
// ---------------------------------------------------------------------------
__global__ void k_pack(const float* __restrict__ W, const float* __restrict__ U,
                       unsigned char* __restrict__ wfrag8, unsigned char* __restrict__ ufrag8) {
    int bid = blockIdx.x;
    const float* src = (bid < 32) ? W : U;
    unsigned char* dstbase = (bid < 32) ? wfrag8 : ufrag8;
    int idx = (bid & 31) * 256 + threadIdx.x;  // 0..8191
    int jg   = idx & 3;
    int lane = (idx >> 2) & 63;
    int tile = idx >> 8;            // kh*16 + nt, 0..31
    int nt = tile & 15, kh = tile >> 4;
    int u  = nt * 16 + (lane & 15);
    int k0 = kh * 128 + (lane >> 4) * 32 + jg * 8;
    unsigned char* dst = dstbase + ((size_t)tile * 64 + lane) * 32 + jg * 8;
    #pragma unroll
    for (int j = 0; j < 8; j++) dst[j] = f2fp8(16.f * src[u * EM + k0 + j]);
}

// ---------------------------------------------------------------------------
// Kernel 2 (fp8): xw[b][t][u] = emb[sent]·W^T via mfma_scale 16x16x128.
// 1024 blocks x 256 thr. Wave w: rows (timesteps) w*16..w*16+15.
// Proven session-best version, unchanged.
// ---------------------------------------------------------------------------
__global__ __launch_bounds__(256, 2) void k_gemm(
    const int* __restrict__ sent, const float* __restrict__ emb,
    const unsigned char* __restrict__ wfrag8, unsigned char* __restrict__ xw8)
{
    __shared__ unsigned char gt[64][272];   // 64 rows x 256 cols fp8, +16 pad
    int w    = threadIdx.x >> 6;
    int lane = threadIdx.x & 63;
    int m  = lane & 15;
    int kg = lane >> 4;
    int row = blockIdx.x * 64 + w * 16 + m;
    int tok = sent[row];
    const float* arow = emb + (size_t)tok * EM;

    // A-frags: quantize this lane's 2 x 32-float slices to fp8 x16
    union { uint32_t d[8]; v8i v; } A[2];
    #pragma unroll
    for (int kh = 0; kh < 2; kh++) {
        const float* p = arow + kh * 128 + kg * 32;
        #pragma unroll
        for (int d = 0; d < 8; d++) {
            float4 f = *(const float4*)(p + 4 * d);
            int pk = __builtin_amdgcn_cvt_pk_fp8_f32(16.f * f.x, 16.f * f.y, 0, false);
            pk     = __builtin_amdgcn_cvt_pk_fp8_f32(16.f * f.z, 16.f * f.w, pk, true);
            A[kh].d[d] = (uint32_t)pk;
        }
    }

    const floatx4 zero4 = {0.f, 0.f, 0.f, 0.f};
    floatx4 acc[16];
    #pragma unroll
    for (int nt = 0; nt < 16; nt++) {
        union { uint4 u4[2]; v8i v; } B0, B1;
        const uint4* p0 = (const uint4*)(wfrag8 + ((size_t)(0 * 16 + nt) * 64 + lane) * 32);
        const uint4* p1 = (const uint4*)(wfrag8 + ((size_t)(1 * 16 + nt) * 64 + lane) * 32);
        B0.u4[0] = p0[0]; B0.u4[1] = p0[1];
        B1.u4[0] = p1[0]; B1.u4[1] = p1[1];
        floatx4 a = __builtin_amdgcn_mfma_scale_f32_16x16x128_f8f6f4(
                        A[0].v, B0.v, zero4, 0, 0, 0, SCALE_Q, 0, SCALE_Q);
        a = __builtin_amdgcn_mfma_scale_f32_16x16x128_f8f6f4(
                        A[1].v, B1.v, a, 0, 0, 0, SCALE_Q, 0, SCALE_Q);
        acc[nt] = a;
    }

    // D: row = w*16 + kg*4 + r (timestep), col = nt*16 + m (unit) -> fp8 x16
    int rloc = w * 16 + kg * 4;
    #pragma unroll
    for (int nt = 0; nt < 16; nt++) {
        #pragma unroll
        for (int r = 0; r < 4; r++) {
            gt[rloc + r][nt * 16 + m] = f2fp8(16.f * acc[nt][r]);
        }
    }
    __syncthreads();

    int rowbase = blockIdx.x * 64;
    #pragma unroll
    for (int r2 = 0; r2 < 16; r2++) {
        int rr = w * 16 + r2;
        uint32_t v = *(const uint32_t*)&gt[rr][lane * 4];
        *(uint32_t*)(xw8 + (size_t)(rowbase + rr) * UN + lane * 4) = v;
    }
}

// ---------------------------------------------------------------------------
// Kernel 3 (v14 == R7, session best, 159.4us): R0's proven scan loop with
// exactly two verified edits:
//   (1) branchless tanh: 1 - 2*rcp(e^{2z}+1)  [-30us vs branchy]
//   (2) head parallelized over 256 threads
// R8 (split accumulators) and R9 (xf->C[0] fold) both measured slower;
// the chained-MFMA + scalar-add form below is the measured optimum.
// ---------------------------------------------------------------------------
__global__ __launch_bounds__(256, 1) void k_rnn(
    const unsigned char* __restrict__ ufrag8, const unsigned char* __restrict__ xw8,
    const float* __restrict__ W1, const float* __restrict__ b1,
    const float* __restrict__ W2, const float* __restrict__ b2,
    float* __restrict__ out)
{
    __shared__ __align__(16) unsigned char hb8[2][256];
    __shared__ __align__(16) unsigned char xstage[64 * 256];   // 16 KB chunk
    __shared__ float partial[256];
    __shared__ float hid[32];
    const int t    = threadIdx.x;
    const int lane = t & 63;
    const int w    = t >> 6;
    const int kg   = lane >> 4;
    const int b    = blockIdx.x;

    // U fp8 B-frags -> registers: ufr8[q][kh], tile nt = 4w+q
    v8i ufr8[4][2];
    #pragma unroll
    for (int q = 0; q < 4; q++) {
        #pragma unroll
        for (int kh = 0; kh < 2; kh++) {
            const uint4* p = (const uint4*)(ufrag8 + ((size_t)(kh * 16 + 4 * w + q) * 64 + lane) * 32);
            union { uint4 u4[2]; v8i v; } cvt;
            cvt.u4[0] = p[0]; cvt.u4[1] = p[1];
            ufr8[q][kh] = cvt.v;
        }
    }

    const unsigned char* xwb = xw8 + (size_t)b * TT * UN;
    const int roff = t * 16;   // byte offset of this thread's 16B refresh slice

    // stage chunk 0 (steps 0..63): 256 thr x 4 x 16B = 16 KB
    uint4 xr[4];
    #pragma unroll
    for (int p = 0; p < 4; p++) xr[p] = *(const uint4*)(xwb + roff + p * 4096);
    #pragma unroll
    for (int p = 0; p < 4; p++) *(uint4*)&xstage[roff + p * 4096] = xr[p];

    hb8[0][t] = 0; hb8[1][t] = 0;
    __syncthreads();

    int cur = 0;
    const floatx4 zero4 = {0.f, 0.f, 0.f, 0.f};
    const int sel = lane >> 4;

    for (int s = 0; s < TT; s++) {
        const int ls = s & 63;
        uint32_t xword = *(const uint32_t*)&xstage[ls * 256 + (t & ~3)];
        float xf = fp8dec(xword, t & 3) * 0.0625f;   // /16

        // A-frags (fp8, 4*h): broadcast 32B reads per k-half
        const unsigned char* hc = hb8[cur];
        union { uint4 u4[2]; v8i v; } A0, A1;
        A0.u4[0] = *(const uint4*)(hc + kg * 32);
        A0.u4[1] = *(const uint4*)(hc + kg * 32 + 16);
        A1.u4[0] = *(const uint4*)(hc + 128 + kg * 32);
        A1.u4[1] = *(const uint4*)(hc + 128 + kg * 32 + 16);

        // 4 tiles, chained K=128 x2 accumulate (measured optimum form)
        float z[4];
        #pragma unroll
        for (int q = 0; q < 4; q++) {
            floatx4 acc = __builtin_amdgcn_mfma_scale_f32_16x16x128_f8f6f4(
                              A0.v, ufr8[q][0], zero4, 0, 0, 0, SCALE_A, 0, SCALE_Q);
            acc = __builtin_amdgcn_mfma_scale_f32_16x16x128_f8f6f4(
                              A1.v, ufr8[q][1], acc, 0, 0, 0, SCALE_A, 0, SCALE_Q);
            z[q] = acc[0];
        }

        float zz = (sel == 0) ? z[0] : (sel == 1) ? z[1] : (sel == 2) ? z[2] : z[3];
        zz += xf;

        // branchless tanh: accurate to ~1e-7, no exec-mask churn
        float e = __expf(2.f * zz);
        float hn = 1.f - 2.f * __builtin_amdgcn_rcpf(e + 1.f);

        hb8[cur ^ 1][t] = f2fp8(4.f * hn);

        if (ls == 60 && s + 68 <= TT) {
            const unsigned char* cb = xwb + (size_t)(s + 4) * UN;
            #pragma unroll
            for (int p = 0; p < 4; p++) xr[p] = *(const uint4*)(cb + roff + p * 4096);
        }
        if (ls == 63 && s + 65 <= TT) {
            BAR();
            #pragma unroll
            for (int p = 0; p < 4; p++) *(uint4*)&xstage[roff + p * 4096] = xr[p];
        }
        BAR();
        cur ^= 1;
    }

    // ---- head: hidden = relu(h @ W1 + b1), parallel over 256 threads
    // thread t: column t&31, K-segment t>>5 (32 of 256 k each); h = fp8/4
    {
        int col = t & 31, seg = t >> 5;
        float a = 0.f;
        #pragma unroll
        for (int kk = 0; kk < 32; kk++) {
            int k = seg * 32 + kk;
            uint32_t wd = *(const uint32_t*)&hb8[cur][k & ~3];
            a += fp8dec(wd, k & 3) * W1[k * 32 + col];
        }
        partial[t] = a;
    }
    __syncthreads();
    if (t < 32) {
        float acc = 0.f;
        #pragma unroll
        for (int i = 0; i < 8; i++) acc += partial[i * 32 + t];
        hid[t] = fmaxf(fmaf(0.25f, acc, b1[t]), 0.f);
    }
    __syncthreads();
    if (t == 0) {
        float l0 = b2[0], l1 = b2[1];
        #pragma unroll
        for (int i = 0; i < 32; i++) {
            float hv = hid[i];
            l0 += hv * W2[2 * i];
            l1 += hv * W2[2 * i + 1];
        }
        float mx2 = fmaxf(l0, l1);
        float e0 = __expf(l0 - mx2), e1 = __expf(l1 - mx2);
        float inv = 1.f / (e0 + e1);
        out[2 * b]     = e0 * inv;
        out[2 * b + 1] = e1 * inv;
    }
}

extern "C" void kernel_launch(void* const* d_in, const int* in_sizes, int n_in,
                              void* d_out, int out_size, void* d_ws, size_t ws_size,
                              hipStream_t stream) {
    const int*   sent = (const int*)d_in[0];
    const float* emb  = (const float*)d_in[1];
    const float* W    = (const float*)d_in[2];
    const float* U    = (const float*)d_in[3];
    const float* W1   = (const float*)d_in[4];
    const float* b1   = (const float*)d_in[5];
    const float* W2   = (const float*)d_in[6];
    const float* b2   = (const float*)d_in[7];
    float* out = (float*)d_out;

    unsigned char* xw8    = (unsigned char*)d_ws;                                   // 16 MB fp8 [B][T][U]
    unsigned char* wfrag8 = (unsigned char*)d_ws + (size_t)NB * TT * UN;            // 64 KB
    unsigned char* ufrag8 = wfrag8 + (size_t)UN * EM;                               // 64 KB

    k_pack<<<64, 256, 0, stream>>>(W, U, wfrag8, ufrag8);
    k_gemm<<<(NB * TT) / 64, 256, 0, stream>>>(sent, emb, wfrag8, xw8);
    k_rnn<<<NB, 256, 0, stream>>>(ufrag8, xw8, W1, b1, W2, b2, out);
}